// Round 4
// baseline (321.221 us; speedup 1.0000x reference)
//
#include <hip/hip_runtime.h>
#include <math.h>

#define BB 32
#define HH 128
#define WW 128
#define CC 64
#define MX 16
#define MY 16
#define NKX 32   // kx modes: 0..15 and 112..127

#define TWOPI 6.283185307179586f

typedef __attribute__((ext_vector_type(8))) short bf16x8;
typedef __attribute__((ext_vector_type(4))) float f32x4;

__device__ inline unsigned short f2bf(float f) {
    union { float f; unsigned u; } v; v.f = f;
    unsigned r = v.u + 0x7FFFu + ((v.u >> 16) & 1u);   // RTNE
    return (unsigned short)(r >> 16);
}

// ws layout (shorts):
//   FR  [4608 slots][8]   : precomputed bf16 fragments, 73,728 B
//       FA   slots [   0,  512)  kA twiddle A-frags
//       FB   slots [ 512, 2560)  kB twiddle A-frags
//       FD   slots [2560, 3584)  kD twiddle A-frags
//       FEAT slots [3584, 4096)  kE A twiddle kstep
//       FEBK slots [4096, 4608)  kE B dense-K ksteps
//   X1  [32][16][128][2][64] bf16   (per (b,ky): row k=2h+ri, col c)
//   X2  [32][32][16][128]           (last dim = 2c+ri)
//   G   [32][32][16][128]           (last dim = 2o+ro)
//   Zf  [32][128][4][512]           (kE B-frag layout: [bh][nt][lane][e])
//
// Fragment convention (verified rounds 2-3):
//   A-frag: lane l=(q=l>>4, r=l&15) holds A[row=r][k=q*8+e]
//   B-frag: lane l holds B[k=q*8+e][col=r]
//   C/D   : acc[j] -> row=q*4+j, col=r

// ---------------- kT: build all block-invariant fragments ----------------
__global__ __launch_bounds__(256) void kT(const float* __restrict__ K, unsigned short* __restrict__ FR) {
    __shared__ float2 tw[128];
    int tid = threadIdx.x;
    if (tid < 128) {
        float s, c;
        sincosf(TWOPI * (float)tid * (1.0f / 128.0f), &s, &c);
        tw[tid] = make_float2(c, s);
    }
    __syncthreads();
    int g = blockIdx.x * 256 + tid;       // 0..4607
    short v[8];
    if (g < 512) {                        // FA: A[row=2ky+ri][w]
        int s = g;
        int l = s & 63, ks = (s >> 6) & 3, mt = s >> 8;
        int q = l >> 4, r = l & 15;
        int row = mt * 16 + r, ky = row >> 1, ri = row & 1;
        int k0 = ks * 32 + q * 8;
        #pragma unroll
        for (int e = 0; e < 8; ++e) {
            float2 t = tw[(ky * (k0 + e)) & 127];
            v[e] = (short)f2bf(ri ? -t.y : t.x);
        }
    } else if (g < 2560) {                // FB: A[row=2kxi+rr][k=2h+ri]
        int s = g - 512;
        int l = s & 63, ks = (s >> 6) & 7, mt = s >> 9;
        int q = l >> 4, r = l & 15;
        int row = mt * 16 + r, kxi = row >> 1, rr = row & 1;
        int kx = (kxi < 16) ? kxi : (96 + kxi);
        int k0 = ks * 32 + q * 8;
        #pragma unroll
        for (int e = 0; e < 8; ++e) {
            int k = k0 + e, h = k >> 1, ri = k & 1;
            float2 t = tw[(kx * h) & 127];
            float val = (rr == 0) ? (ri == 0 ? t.x : t.y) : (ri == 0 ? -t.y : t.x);
            v[e] = (short)f2bf(val);
        }
    } else if (g < 3584) {                // FD: A[row=h][k=2kxi+ri]
        int s = g - 2560;
        int l = s & 63, ks = (s >> 6) & 1, mt = s >> 7;
        int q = l >> 4, r = l & 15;
        int h = mt * 16 + r;
        int k0 = ks * 32 + q * 8;
        #pragma unroll
        for (int e = 0; e < 8; ++e) {
            int k = k0 + e, kxi = k >> 1, ri = k & 1;
            int kx = (kxi < 16) ? kxi : (96 + kxi);
            float2 t = tw[(kx * h) & 127];
            v[e] = (short)f2bf(ri == 0 ? t.x : -t.y);
        }
    } else if (g < 4096) {                // FEAT: kE A ks=2 (inverse-ky twiddles, scaled)
        int s = g - 3584;
        int l = s & 63, tm = s >> 6;
        int q = l >> 4, r = l & 15;
        int row = tm * 16 + r;
        const float inv = 1.0f / 16384.0f;
        #pragma unroll
        for (int e = 0; e < 8; ++e) {
            int ky = 4 * q + (e >> 1);
            float sc = ((ky == 0) ? 1.0f : 2.0f) * inv;
            float2 t = tw[(ky * row) & 127];
            v[e] = (short)f2bf((e & 1) ? (-t.y * sc) : (t.x * sc));
        }
    } else {                              // FEBK: kE B ks=0,1 (dense kernel K)
        int s = g - 4096;
        int l = s & 63, ks = (s >> 6) & 1, nt = s >> 7;
        int q = l >> 4, r = l & 15;
        int col = nt * 16 + r;
        #pragma unroll
        for (int e = 0; e < 8; ++e) {
            int k = ks * 32 + q * 8 + e;
            v[e] = (short)f2bf(K[k * CC + col]);
        }
    }
    *(bf16x8*)&FR[(size_t)g * 8] = *(const bf16x8*)v;
}

// ---------------- kA: DFT over w as GEMM [32 x 128] @ [128 x 64] per (b,h) ----------------
__global__ __launch_bounds__(256) void kA(const float* __restrict__ x, const unsigned short* __restrict__ FR,
                                          unsigned short* __restrict__ X1) {
    int tid = threadIdx.x, bh = blockIdx.x;
    int lane = tid & 63, nt = tid >> 6, q = lane >> 4, r = lane & 15;
    const float* xp = x + (size_t)bh * (WW * CC);
    bf16x8 bf[4];
    #pragma unroll
    for (int ks = 0; ks < 4; ++ks) {
        short v[8];
        #pragma unroll
        for (int e = 0; e < 8; ++e)
            v[e] = (short)f2bf(xp[(ks * 32 + q * 8 + e) * CC + nt * 16 + r]);
        bf[ks] = *(const bf16x8*)v;
    }
    f32x4 acc0 = {0.f, 0.f, 0.f, 0.f}, acc1 = {0.f, 0.f, 0.f, 0.f};
    #pragma unroll
    for (int ks = 0; ks < 4; ++ks) {
        bf16x8 a0 = *(const bf16x8*)&FR[((size_t)((0 * 4 + ks) * 64 + lane)) * 8];
        bf16x8 a1 = *(const bf16x8*)&FR[((size_t)((1 * 4 + ks) * 64 + lane)) * 8];
        acc0 = __builtin_amdgcn_mfma_f32_16x16x32_bf16(a0, bf[ks], acc0, 0, 0, 0);
        acc1 = __builtin_amdgcn_mfma_f32_16x16x32_bf16(a1, bf[ks], acc1, 0, 0, 0);
    }
    int b = bh >> 7, h = bh & 127;
    int c = nt * 16 + r;
    #pragma unroll
    for (int j = 0; j < 4; ++j) {
        int m0 = q * 4 + j;
        X1[(((size_t)b * 16 + (m0 >> 1)) * 128 + h) * 128 + (m0 & 1) * 64 + c] = f2bf(acc0[j]);
        int m1 = 16 + m0;
        X1[(((size_t)b * 16 + (m1 >> 1)) * 128 + h) * 128 + (m1 & 1) * 64 + c] = f2bf(acc1[j]);
    }
}

// ---------------- kB: DFT over h as GEMM [64 x 256] @ [256 x 64] per (b,ky) ----------------
__global__ __launch_bounds__(256) void kB(const unsigned short* __restrict__ X1, const unsigned short* __restrict__ FR,
                                          unsigned short* __restrict__ X2) {
    int tid = threadIdx.x, blk = blockIdx.x;   // b*16 + ky
    int b = blk >> 4, ky = blk & 15;
    const unsigned short* FB = FR + 4096;      // slot 512
    const unsigned short* p = X1 + ((size_t)b * 16 + ky) * 16384;   // [k=2h+ri][c]
    int lane = tid & 63, wid = tid >> 6, q = lane >> 4, r = lane & 15;
    int col = wid * 16 + r;
    bf16x8 bf[8];
    #pragma unroll
    for (int ks = 0; ks < 8; ++ks) {
        short v[8];
        #pragma unroll
        for (int e = 0; e < 8; ++e)
            v[e] = (short)p[(ks * 32 + q * 8 + e) * 64 + col];
        bf[ks] = *(const bf16x8*)v;
    }
    #pragma unroll
    for (int mt = 0; mt < 4; ++mt) {
        f32x4 acc = {0.f, 0.f, 0.f, 0.f};
        #pragma unroll
        for (int ks = 0; ks < 8; ++ks) {
            bf16x8 a = *(const bf16x8*)&FB[((size_t)((mt * 8 + ks) * 64 + lane)) * 8];
            acc = __builtin_amdgcn_mfma_f32_16x16x32_bf16(a, bf[ks], acc, 0, 0, 0);
        }
        #pragma unroll
        for (int j = 0; j < 4; ++j) {
            int m = mt * 16 + q * 4 + j;
            int kxi = m >> 1, rr = m & 1;
            X2[(((size_t)b * NKX + kxi) * 16 + ky) * 128 + 2 * col + rr] = f2bf(acc[j]);
        }
    }
}

// ---------------- kC: channel mix as GEMM [32 x 128] @ [128 x 128] per mode ----------------
__global__ __launch_bounds__(256) void kC(const float* __restrict__ w1r, const float* __restrict__ w1i,
                                          const float* __restrict__ w2r, const float* __restrict__ w2i,
                                          const unsigned short* __restrict__ X2, unsigned short* __restrict__ G) {
    __shared__ float wsr[CC * CC];
    __shared__ float wsi[CC * CC];
    int tid = threadIdx.x;
    int blk = blockIdx.x;             // kxi*16 + ky
    int kxi = blk >> 4, ky = blk & 15;
    const float* wr = (kxi < 16) ? w1r : w2r;
    const float* wi = (kxi < 16) ? w1i : w2i;
    int wx = (kxi < 16) ? kxi : (kxi - 16);
    size_t woff = ((size_t)wx * MY + ky) * (CC * CC);
    for (int i = tid * 4; i < CC * CC; i += 1024) {
        *(float4*)&wsr[i] = *(const float4*)&wr[woff + i];
        *(float4*)&wsi[i] = *(const float4*)&wi[woff + i];
    }
    __syncthreads();

    int lane = tid & 63, wid = tid >> 6;
    int q = lane >> 4, r = lane & 15;
    bf16x8 af[2][4];
    #pragma unroll
    for (int mt = 0; mt < 2; ++mt) {
        int b = mt * 16 + r;
        #pragma unroll
        for (int ks = 0; ks < 4; ++ks)
            af[mt][ks] = *(const bf16x8*)&X2[(((size_t)b * NKX + kxi) * 16 + ky) * 128 + ks * 32 + q * 8];
    }
    bf16x8 bfr[2][4];
    #pragma unroll
    for (int t = 0; t < 2; ++t) {
        int n = (wid * 2 + t) * 16 + r;
        int o = n >> 1, ro = n & 1;
        #pragma unroll
        for (int ks = 0; ks < 4; ++ks) {
            short v[8];
            #pragma unroll
            for (int e = 0; e < 8; ++e) {
                int k = ks * 32 + q * 8 + e;
                int i = k >> 1, ri = k & 1;
                float val = (ri == 0) ? (ro ? wsi[i * 64 + o] : wsr[i * 64 + o])
                                      : (ro ? wsr[i * 64 + o] : -wsi[i * 64 + o]);
                v[e] = (short)f2bf(val);
            }
            bfr[t][ks] = *(const bf16x8*)v;
        }
    }
    f32x4 acc[2][2] = {{{0.f,0.f,0.f,0.f},{0.f,0.f,0.f,0.f}},{{0.f,0.f,0.f,0.f},{0.f,0.f,0.f,0.f}}};
    #pragma unroll
    for (int ks = 0; ks < 4; ++ks)
        #pragma unroll
        for (int mt = 0; mt < 2; ++mt)
            #pragma unroll
            for (int t = 0; t < 2; ++t)
                acc[mt][t] = __builtin_amdgcn_mfma_f32_16x16x32_bf16(af[mt][ks], bfr[t][ks], acc[mt][t], 0, 0, 0);
    #pragma unroll
    for (int mt = 0; mt < 2; ++mt)
        #pragma unroll
        for (int t = 0; t < 2; ++t)
            #pragma unroll
            for (int j = 0; j < 4; ++j) {
                int b = mt * 16 + q * 4 + j;
                int n = (wid * 2 + t) * 16 + r;
                G[(((size_t)b * NKX + kxi) * 16 + ky) * 128 + n] = f2bf(acc[mt][t][j]);
            }
}

// ---------------- kD: inverse DFT over kx, writes Z in kE fragment layout ----------------
__global__ __launch_bounds__(256) void kD(const unsigned short* __restrict__ G, const unsigned short* __restrict__ FR,
                                          unsigned short* __restrict__ Zf) {
    int tid = threadIdx.x, blk = blockIdx.x;   // b*32 + ky*2 + mh
    int b = blk >> 5, ky = (blk >> 1) & 15, mh = blk & 1;
    int lane = tid & 63, wid = tid >> 6, q = lane >> 4, r = lane & 15;
    const unsigned short* FD = FR + 20480;     // slot 2560
    // B[k=2kxi+ri][n=2c+ro] = G[..][n ^ ri], negated iff ri & (n&1)
    bf16x8 bfr[2][2];
    #pragma unroll
    for (int t = 0; t < 2; ++t) {
        int n = (wid * 2 + t) * 16 + r;
        #pragma unroll
        for (int ks = 0; ks < 2; ++ks) {
            short v[8];
            #pragma unroll
            for (int e = 0; e < 8; ++e) {
                int k = ks * 32 + q * 8 + e;
                int kxi = k >> 1, ri = k & 1;
                unsigned short raw = G[(((size_t)b * NKX + kxi) * 16 + ky) * 128 + (n ^ ri)];
                if (ri & (n & 1)) raw ^= 0x8000u;
                v[e] = (short)raw;
            }
            bfr[t][ks] = *(const bf16x8*)v;
        }
    }
    #pragma unroll
    for (int mt2 = 0; mt2 < 4; ++mt2) {
        int mt = mh * 4 + mt2;
        f32x4 acc[2] = {{0.f,0.f,0.f,0.f},{0.f,0.f,0.f,0.f}};
        #pragma unroll
        for (int ks = 0; ks < 2; ++ks) {
            bf16x8 a = *(const bf16x8*)&FD[((size_t)((mt * 2 + ks) * 64 + lane)) * 8];
            #pragma unroll
            for (int t = 0; t < 2; ++t)
                acc[t] = __builtin_amdgcn_mfma_f32_16x16x32_bf16(a, bfr[t][ks], acc[t], 0, 0, 0);
        }
        #pragma unroll
        for (int t = 0; t < 2; ++t)
            #pragma unroll
            for (int j = 0; j < 4; ++j) {
                int h = mt * 16 + q * 4 + j;
                int n = (wid * 2 + t) * 16 + r;
                int c = n >> 1, reim = n & 1;
                int kp = 2 * ky + reim, q2 = kp >> 3, e2 = kp & 7;
                int nt2 = c >> 4, r2 = c & 15;
                Zf[(((size_t)b * 128 + h) * 4 + nt2) * 512 + (q2 * 16 + r2) * 8 + e2] = f2bf(acc[t][j]);
            }
    }
}

// ---------------- kE: MFMA GEMM  out = GELU(x + [x|T]@[K;Z] + bias) ----------------
__global__ __launch_bounds__(256) void kE(const float* __restrict__ x, const unsigned short* __restrict__ Zf,
                                          const unsigned short* __restrict__ FR,
                                          const float* __restrict__ bias, float* __restrict__ out) {
    __shared__ float xs[WW * 68];              // pad 64->68: 2-way-free banks on b128 reads
    int tid = threadIdx.x, bh = blockIdx.x;
    const float* xp = x + (size_t)bh * (WW * CC);
    for (int i = tid * 4; i < WW * CC; i += 1024) {
        int w = i >> 6, c = i & 63;
        *(float4*)&xs[w * 68 + c] = *(const float4*)&xp[i];
    }
    __syncthreads();
    int lane = tid & 63, wv = tid >> 6, q = lane >> 4, r = lane & 15;
    const unsigned short* FEAT = FR + 28672;   // slot 3584
    const unsigned short* FEBK = FR + 32768;   // slot 4096
    bf16x8 ax[2][2], at[2];
    #pragma unroll
    for (int t2 = 0; t2 < 2; ++t2) {
        int tm = wv * 2 + t2;
        int row = tm * 16 + r;
        #pragma unroll
        for (int ks = 0; ks < 2; ++ks) {
            const float* s = &xs[row * 68 + ks * 32 + q * 8];
            short v[8];
            #pragma unroll
            for (int e = 0; e < 8; ++e) v[e] = (short)f2bf(s[e]);
            ax[t2][ks] = *(const bf16x8*)v;
        }
        at[t2] = *(const bf16x8*)&FEAT[((size_t)(tm * 64 + lane)) * 8];
    }
    #pragma unroll
    for (int nt = 0; nt < 4; ++nt) {
        bf16x8 b0 = *(const bf16x8*)&FEBK[((size_t)((nt * 2 + 0) * 64 + lane)) * 8];
        bf16x8 b1 = *(const bf16x8*)&FEBK[((size_t)((nt * 2 + 1) * 64 + lane)) * 8];
        bf16x8 bz = *(const bf16x8*)&Zf[((size_t)bh * 4 + nt) * 512 + lane * 8];
        int c = nt * 16 + r;
        float bsv = bias[c];
        #pragma unroll
        for (int t2 = 0; t2 < 2; ++t2) {
            int tm = wv * 2 + t2;
            f32x4 acc = {0.f, 0.f, 0.f, 0.f};
            acc = __builtin_amdgcn_mfma_f32_16x16x32_bf16(ax[t2][0], b0, acc, 0, 0, 0);
            acc = __builtin_amdgcn_mfma_f32_16x16x32_bf16(ax[t2][1], b1, acc, 0, 0, 0);
            acc = __builtin_amdgcn_mfma_f32_16x16x32_bf16(at[t2], bz, acc, 0, 0, 0);
            #pragma unroll
            for (int j = 0; j < 4; ++j) {
                int w = tm * 16 + q * 4 + j;
                float u = acc[j] + xs[w * 68 + c] + bsv;
                float t = u + 0.044715f * u * u * u;
                float e = __expf(-1.5957691216057308f * t);
                out[(size_t)bh * (WW * CC) + w * CC + c] = u / (1.0f + e);
            }
        }
    }
}

extern "C" void kernel_launch(void* const* d_in, const int* in_sizes, int n_in,
                              void* d_out, int out_size, void* d_ws, size_t ws_size,
                              hipStream_t stream) {
    const float* x   = (const float*)d_in[0];
    const float* w1r = (const float*)d_in[1];
    const float* w1i = (const float*)d_in[2];
    const float* w2r = (const float*)d_in[3];
    const float* w2i = (const float*)d_in[4];
    const float* dk  = (const float*)d_in[5];
    const float* db  = (const float*)d_in[6];
    float* out = (float*)d_out;

    unsigned short* FR = (unsigned short*)d_ws;      // 4608*8 shorts (73,728 B), padded to 128 KB
    unsigned short* X1 = FR + 65536;                 // 8,388,608 elems
    unsigned short* X2 = X1 + 8388608;               // 2,097,152 elems
    unsigned short* G  = X2 + 2097152;               // 2,097,152 elems
    unsigned short* Zf = G  + 2097152;               // 8,388,608 elems

    kT<<<18, 256, 0, stream>>>(dk, FR);
    kA<<<BB * HH, 256, 0, stream>>>(x, FR, X1);
    kB<<<BB * MY, 256, 0, stream>>>(X1, FR, X2);
    kC<<<NKX * MY, 256, 0, stream>>>(w1r, w1i, w2r, w2i, X2, G);
    kD<<<BB * MY * 2, 256, 0, stream>>>(G, FR, Zf);
    kE<<<BB * HH, 256, 0, stream>>>(x, Zf, FR, db, out);
}